// Round 12
// baseline (354.985 us; speedup 1.0000x reference)
//
#include <hip/hip_runtime.h>
#include <hip/hip_fp16.h>
#include <cstdint>
#include <cstddef>

static constexpr int N1 = 40000;
static constexpr int N2 = 10000;
static constexpr int KNN = 16;
static constexpr float EPS = 1e-5f;

// Workspace layout (float offsets; fp16 regions reinterpret the same slots)
static constexpr size_t OFF_Y1   = 0;          // N1*64 f32 raw linear1 output
static constexpr size_t OFF_Y2   = 2560000;    // N2*64 f32 raw linear2 output
static constexpr size_t OFF_XQH  = 5760000;    // N1*64 __half
static constexpr size_t OFF_XKH  = 8320000;    // N1*64 __half
static constexpr size_t OFF_XVPH = 10880000;   // N1*64 __half (PERMUTED [j][d*8+s])
static constexpr size_t OFF_W1BH = 13440000;   // N1*16*8 __half
static constexpr size_t OFF_ST   = 18560000;   // st1(128) st2(128) st0(128) stw1(16)

union F4H8 { float4 f4; __half2 h2[4]; };

typedef _Float16 f16x8 __attribute__((ext_vector_type(8)));
typedef float f32x4 __attribute__((ext_vector_type(4)));
union H8V { __half2 h2[4]; f16x8 v; };

__device__ __forceinline__ void cvt8(float4 raw, float* u) {
    F4H8 c; c.f4 = raw;
#pragma unroll
    for (int t = 0; t < 4; t++) {
        float2 f = __half22float2(c.h2[t]);
        u[2 * t] = f.x; u[2 * t + 1] = f.y;
    }
}

// packed relu: per-component max with 0
__device__ __forceinline__ __half2 relu2(__half2 a) {
    const __half z = __float2half_rn(0.f);
    __half2 r;
    r.x = __hmax(a.x, z);
    r.y = __hmax(a.y, z);
    return r;
}

// ---------------------------------------------------------------------------
// MFMA GEMM + column stats (r11-verified): Y = fp16(X) @ fp16(W), f32 acc.
// lane = (c16 = A-row, q = K-quad); B[k][n]: n=lane&15, k=q*8+j.
// C/D: col=lane&15, row=q*4+r. Block = 256 rows.
// ---------------------------------------------------------------------------
template<int CIN>
__device__ __forceinline__ void gemm_mfma_stats_body(const float* __restrict__ X,
                                                     float* __restrict__ Y,
                                                     float* __restrict__ stats,
                                                     int rowbase, int nrows,
                                                     const float* __restrict__ Wsm)
{
    constexpr int KC = CIN / 32;
    const int lane = threadIdx.x & 63, wv = threadIdx.x >> 6;
    const int c16 = lane & 15, q = lane >> 4;

    H8V b[4][KC];
#pragma unroll
    for (int g = 0; g < 4; g++)
#pragma unroll
        for (int h = 0; h < KC; h++)
#pragma unroll
            for (int j = 0; j < 8; j += 2) {
                int k0 = h * 32 + q * 8 + j;
                b[g][h].h2[j / 2] = __floats2half2_rn(Wsm[k0 * 64 + g * 16 + c16],
                                                      Wsm[(k0 + 1) * 64 + g * 16 + c16]);
            }

    float sA[4] = {0.f, 0.f, 0.f, 0.f}, sQ[4] = {0.f, 0.f, 0.f, 0.f};

#pragma unroll
    for (int it = 0; it < 4; it++) {
        const int r0 = wv * 64 + it * 16;
        const bool valid = (r0 + c16) < nrows;
        const int grow = rowbase + r0 + c16;
        H8V a[KC];
#pragma unroll
        for (int h = 0; h < KC; h++) {
            float4 xa = make_float4(0.f, 0.f, 0.f, 0.f);
            float4 xb = make_float4(0.f, 0.f, 0.f, 0.f);
            if (valid) {
                xa = *(const float4*)(X + (size_t)grow * CIN + h * 32 + q * 8);
                xb = *(const float4*)(X + (size_t)grow * CIN + h * 32 + q * 8 + 4);
            }
            a[h].h2[0] = __floats2half2_rn(xa.x, xa.y);
            a[h].h2[1] = __floats2half2_rn(xa.z, xa.w);
            a[h].h2[2] = __floats2half2_rn(xb.x, xb.y);
            a[h].h2[3] = __floats2half2_rn(xb.z, xb.w);
        }
        f32x4 acc[4];
#pragma unroll
        for (int g = 0; g < 4; g++) acc[g] = (f32x4){0.f, 0.f, 0.f, 0.f};
#pragma unroll
        for (int h = 0; h < KC; h++)
#pragma unroll
            for (int g = 0; g < 4; g++)
                acc[g] = __builtin_amdgcn_mfma_f32_16x16x32_f16(a[h].v, b[g][h].v,
                                                                acc[g], 0, 0, 0);
#pragma unroll
        for (int g = 0; g < 4; g++)
#pragma unroll
            for (int r = 0; r < 4; r++) {
                int rr = r0 + q * 4 + r;
                if (rr < nrows)
                    Y[(size_t)(rowbase + rr) * 64 + g * 16 + c16] = acc[g][r];
                sA[g] += acc[g][r];
                sQ[g] += acc[g][r] * acc[g][r];
            }
    }
#pragma unroll
    for (int off = 16; off <= 32; off <<= 1)
#pragma unroll
        for (int g = 0; g < 4; g++) {
            sA[g] += __shfl_xor(sA[g], off);
            sQ[g] += __shfl_xor(sQ[g], off);
        }
    if (q == 0) {
#pragma unroll
        for (int g = 0; g < 4; g++) {
            atomicAdd(&stats[g * 16 + c16], sA[g]);
            atomicAdd(&stats[64 + g * 16 + c16], sQ[g]);
        }
    }
}

__global__ __launch_bounds__(256) void stats12_k(const float* __restrict__ x1,
                                                 const float* __restrict__ W1,
                                                 const float* __restrict__ x2,
                                                 const float* __restrict__ W2,
                                                 float* __restrict__ y1,
                                                 float* __restrict__ y2,
                                                 float* __restrict__ st1,
                                                 float* __restrict__ st2)
{
    __shared__ float Wsm[128 * 64];
    if (blockIdx.x < 157) {
        for (int t = threadIdx.x; t < 64 * 64; t += 256) Wsm[t] = W1[t];
        __syncthreads();
        int rowbase = blockIdx.x * 256;
        gemm_mfma_stats_body<64>(x1, y1, st1, rowbase, N1 - rowbase, Wsm);
    } else {
        for (int t = threadIdx.x; t < 128 * 64; t += 256) Wsm[t] = W2[t];
        __syncthreads();
        int rowbase = (blockIdx.x - 157) * 256;
        gemm_mfma_stats_body<128>(x2, y2, st2, rowbase, N2 - rowbase, Wsm);
    }
}

// ---------------------------------------------------------------------------
// qkv (MFMA): blocks [0,157): xqh = fp16(relu(bn1(y1)) @ Wq + bq), 256 rows/blk
//             blocks [157,782): x2i = interp(relu(bn2(y2))) -> Xs (LDS f32);
//               xkh = fp16(Xs@Wk); xvph = fp16(perm(Xs@Wv + bv)); 64 rows/blk
// LDS kv: [Wks 4096][Wvs 4096][Xs 64x68=4352][cst 128] = 12672 (cst at 12544!)
// ---------------------------------------------------------------------------
__global__ __launch_bounds__(256) void qkv_k(const float* __restrict__ y1,
                                             const float* __restrict__ st1,
                                             const float* __restrict__ g1,
                                             const float* __restrict__ be1,
                                             const float* __restrict__ Wq,
                                             const float* __restrict__ bq,
                                             const float* __restrict__ p1,
                                             const float* __restrict__ p2,
                                             const int* __restrict__ iidx,
                                             const float* __restrict__ y2,
                                             const float* __restrict__ st2,
                                             const float* __restrict__ g2,
                                             const float* __restrict__ be2,
                                             const float* __restrict__ Wk_,
                                             const float* __restrict__ Wv_,
                                             const float* __restrict__ bv_,
                                             __half* __restrict__ xqh,
                                             __half* __restrict__ xkh,
                                             __half* __restrict__ xvph)
{
    __shared__ float sm[12672];
    const int lane = threadIdx.x & 63, wv = threadIdx.x >> 6;
    const int c16 = lane & 15, q = lane >> 4;

    if (blockIdx.x < 157) {
        float* Ws = sm;                 // 4096
        float* cst = sm + 4096;         // 128
        for (int t = threadIdx.x; t < 4096; t += 256) Ws[t] = Wq[t];
        if (threadIdx.x < 64) {
            int c = threadIdx.x;
            float mean = st1[c] * (1.f / N1);
            float var = st1[64 + c] * (1.f / N1) - mean * mean;
            float sg = g1[c] * rsqrtf(var + EPS);
            cst[c] = sg; cst[64 + c] = be1[c] - mean * sg;
        }
        __syncthreads();

        H8V b[4][2];
#pragma unroll
        for (int g = 0; g < 4; g++)
#pragma unroll
            for (int h = 0; h < 2; h++)
#pragma unroll
                for (int j = 0; j < 8; j += 2) {
                    int k0 = h * 32 + q * 8 + j;
                    b[g][h].h2[j / 2] = __floats2half2_rn(Ws[k0 * 64 + g * 16 + c16],
                                                          Ws[(k0 + 1) * 64 + g * 16 + c16]);
                }
        float scq[16], shq[16];
#pragma unroll
        for (int h = 0; h < 2; h++)
#pragma unroll
            for (int j = 0; j < 8; j++) {
                int c = h * 32 + q * 8 + j;
                scq[h * 8 + j] = cst[c]; shq[h * 8 + j] = cst[64 + c];
            }
        float bqv[4];
#pragma unroll
        for (int g = 0; g < 4; g++) bqv[g] = bq[g * 16 + c16];

        const int rowbase = blockIdx.x * 256;
        const int nrows = N1 - rowbase;
#pragma unroll
        for (int it = 0; it < 4; it++) {
            const int r0 = wv * 64 + it * 16;
            const bool valid = (r0 + c16) < nrows;
            const int grow = rowbase + r0 + c16;
            H8V a[2];
#pragma unroll
            for (int h = 0; h < 2; h++) {
                float u[8];
#pragma unroll
                for (int j = 0; j < 8; j++) u[j] = 0.f;
                if (valid) {
                    float4 xa = *(const float4*)(y1 + (size_t)grow * 64 + h * 32 + q * 8);
                    float4 xb = *(const float4*)(y1 + (size_t)grow * 64 + h * 32 + q * 8 + 4);
                    u[0] = xa.x; u[1] = xa.y; u[2] = xa.z; u[3] = xa.w;
                    u[4] = xb.x; u[5] = xb.y; u[6] = xb.z; u[7] = xb.w;
#pragma unroll
                    for (int j = 0; j < 8; j++)
                        u[j] = fmaxf(u[j] * scq[h * 8 + j] + shq[h * 8 + j], 0.f);
                }
#pragma unroll
                for (int t = 0; t < 4; t++)
                    a[h].h2[t] = __floats2half2_rn(u[2 * t], u[2 * t + 1]);
            }
            f32x4 acc[4];
#pragma unroll
            for (int g = 0; g < 4; g++) acc[g] = (f32x4){0.f, 0.f, 0.f, 0.f};
#pragma unroll
            for (int h = 0; h < 2; h++)
#pragma unroll
                for (int g = 0; g < 4; g++)
                    acc[g] = __builtin_amdgcn_mfma_f32_16x16x32_f16(a[h].v, b[g][h].v,
                                                                    acc[g], 0, 0, 0);
#pragma unroll
            for (int g = 0; g < 4; g++)
#pragma unroll
                for (int r = 0; r < 4; r++) {
                    int rr = r0 + q * 4 + r;
                    if (rr < nrows)
                        xqh[(size_t)(rowbase + rr) * 64 + g * 16 + c16] =
                            __float2half_rn(acc[g][r] + bqv[g]);
                }
        }
    } else {
        float* Wks = sm;                // 4096
        float* Wvs = sm + 4096;         // 4096
        float* Xs = sm + 8192;          // 64 x 68 -> ends 12544
        float* cst = sm + 12544;        // 128
        for (int t = threadIdx.x; t < 4096; t += 256) { Wks[t] = Wk_[t]; Wvs[t] = Wv_[t]; }
        if (threadIdx.x < 64) {
            int c = threadIdx.x;
            float mean = st2[c] * (1.f / N2);
            float var = st2[64 + c] * (1.f / N2) - mean * mean;
            float sg = g2[c] * rsqrtf(var + EPS);
            cst[c] = sg; cst[64 + c] = be2[c] - mean * sg;
        }
        __syncthreads();
        const int base = (blockIdx.x - 157) * 64;
        {   // interp fill: thread = (row, quarter)
            int row = threadIdx.x >> 2, q4 = threadIdx.x & 3;
            int gi = base + row;
            int j0 = iidx[gi * 3 + 0], j1 = iidx[gi * 3 + 1], j2 = iidx[gi * 3 + 2];
            float ax = p1[gi * 3 + 0], ay = p1[gi * 3 + 1], az = p1[gi * 3 + 2];
            float dx, dy, dz;
            dx = ax - p2[j0 * 3 + 0]; dy = ay - p2[j0 * 3 + 1]; dz = az - p2[j0 * 3 + 2];
            float w0 = 1.f / (sqrtf(dx * dx + dy * dy + dz * dz) + 1e-8f);
            dx = ax - p2[j1 * 3 + 0]; dy = ay - p2[j1 * 3 + 1]; dz = az - p2[j1 * 3 + 2];
            float w1 = 1.f / (sqrtf(dx * dx + dy * dy + dz * dz) + 1e-8f);
            dx = ax - p2[j2 * 3 + 0]; dy = ay - p2[j2 * 3 + 1]; dz = az - p2[j2 * 3 + 2];
            float w2 = 1.f / (sqrtf(dx * dx + dy * dy + dz * dz) + 1e-8f);
            float inv = 1.f / (w0 + w1 + w2);
            w0 *= inv; w1 *= inv; w2 *= inv;
#pragma unroll
            for (int c4 = 0; c4 < 4; c4++) {
                int col = q4 * 16 + c4 * 4;
                float4 a = *(const float4*)(y2 + (size_t)j0 * 64 + col);
                float4 b = *(const float4*)(y2 + (size_t)j1 * 64 + col);
                float4 c = *(const float4*)(y2 + (size_t)j2 * 64 + col);
                float4 o;
                o.x = w0 * fmaxf(a.x * cst[col] + cst[64 + col], 0.f)
                    + w1 * fmaxf(b.x * cst[col] + cst[64 + col], 0.f)
                    + w2 * fmaxf(c.x * cst[col] + cst[64 + col], 0.f);
                o.y = w0 * fmaxf(a.y * cst[col + 1] + cst[64 + col + 1], 0.f)
                    + w1 * fmaxf(b.y * cst[col + 1] + cst[64 + col + 1], 0.f)
                    + w2 * fmaxf(c.y * cst[col + 1] + cst[64 + col + 1], 0.f);
                o.z = w0 * fmaxf(a.z * cst[col + 2] + cst[64 + col + 2], 0.f)
                    + w1 * fmaxf(b.z * cst[col + 2] + cst[64 + col + 2], 0.f)
                    + w2 * fmaxf(c.z * cst[col + 2] + cst[64 + col + 2], 0.f);
                o.w = w0 * fmaxf(a.w * cst[col + 3] + cst[64 + col + 3], 0.f)
                    + w1 * fmaxf(b.w * cst[col + 3] + cst[64 + col + 3], 0.f)
                    + w2 * fmaxf(c.w * cst[col + 3] + cst[64 + col + 3], 0.f);
                *(float4*)(Xs + row * 68 + col) = o;
            }
        }
        __syncthreads();

        // B fragments for Wk and Wv
        H8V bk[4][2], bvv[4][2];
#pragma unroll
        for (int g = 0; g < 4; g++)
#pragma unroll
            for (int h = 0; h < 2; h++)
#pragma unroll
                for (int j = 0; j < 8; j += 2) {
                    int k0 = h * 32 + q * 8 + j;
                    bk[g][h].h2[j / 2] = __floats2half2_rn(Wks[k0 * 64 + g * 16 + c16],
                                                           Wks[(k0 + 1) * 64 + g * 16 + c16]);
                    bvv[g][h].h2[j / 2] = __floats2half2_rn(Wvs[k0 * 64 + g * 16 + c16],
                                                            Wvs[(k0 + 1) * 64 + g * 16 + c16]);
                }
        float bvb[4];
#pragma unroll
        for (int g = 0; g < 4; g++) bvb[g] = bv_[g * 16 + c16];

        // A fragments from Xs: wave wv covers rows wv*16..wv*16+15
        H8V a[2];
#pragma unroll
        for (int h = 0; h < 2; h++) {
            const float* xp = Xs + (wv * 16 + c16) * 68 + h * 32 + q * 8;
            float4 xa = *(const float4*)xp;
            float4 xb = *(const float4*)(xp + 4);
            a[h].h2[0] = __floats2half2_rn(xa.x, xa.y);
            a[h].h2[1] = __floats2half2_rn(xa.z, xa.w);
            a[h].h2[2] = __floats2half2_rn(xb.x, xb.y);
            a[h].h2[3] = __floats2half2_rn(xb.z, xb.w);
        }
        f32x4 acck[4], accv[4];
#pragma unroll
        for (int g = 0; g < 4; g++) {
            acck[g] = (f32x4){0.f, 0.f, 0.f, 0.f};
            accv[g] = (f32x4){0.f, 0.f, 0.f, 0.f};
        }
#pragma unroll
        for (int h = 0; h < 2; h++)
#pragma unroll
            for (int g = 0; g < 4; g++) {
                acck[g] = __builtin_amdgcn_mfma_f32_16x16x32_f16(a[h].v, bk[g][h].v,
                                                                 acck[g], 0, 0, 0);
                accv[g] = __builtin_amdgcn_mfma_f32_16x16x32_f16(a[h].v, bvv[g][h].v,
                                                                 accv[g], 0, 0, 0);
            }
        // xk stores (C/D: row = q*4+r within the wave's 16 rows, col = g*16+c16)
#pragma unroll
        for (int g = 0; g < 4; g++)
#pragma unroll
            for (int r = 0; r < 4; r++) {
                int grow = base + wv * 16 + q * 4 + r;
                xkh[(size_t)grow * 64 + g * 16 + c16] = __float2half_rn(acck[g][r]);
            }
        // xvp via LDS bounce (permuted channel), reusing sm[0..4096)
        __syncthreads();                    // all LDS reads (Wks/Wvs/Xs) done
        __half* hb = (__half*)sm;           // 64 rows x 64 halves
#pragma unroll
        for (int g = 0; g < 4; g++)
#pragma unroll
            for (int r = 0; r < 4; r++) {
                int c = g * 16 + c16;
                int pc = (c & 7) * 8 + (c >> 3);
                hb[(wv * 16 + q * 4 + r) * 64 + pc] = __float2half_rn(accv[g][r] + bvb[g]);
            }
        __syncthreads();
        for (int f = threadIdx.x; f < 512; f += 256) {
            float4 v = *(const float4*)((const char*)hb + f * 16);
            ((float4*)(xvph + (size_t)base * 64))[f] = v;
        }
    }
}

// ---------------------------------------------------------------------------
// wstats: per-channel sum/sumsq of w = xk[knn]-xq. lane=(k8,ch);
// 8 nodes/wave, depth-2 rolling prefetch. grid = 1250. (r7 version)
// ---------------------------------------------------------------------------
__global__ __launch_bounds__(256) void wstats_k(const __half* __restrict__ xqh,
                                                const __half* __restrict__ xkh,
                                                const int* __restrict__ knn,
                                                float* __restrict__ st0)
{
    __shared__ int ibuf[4][128];
    __shared__ float red[4][128];
    const int lane = threadIdx.x & 63, wv = threadIdx.x >> 6;
    const int k8 = lane >> 3, ch = lane & 7;
    const int nbase = blockIdx.x * 32 + wv * 8;

    ibuf[wv][lane] = knn[nbase * 16 + lane];
    ibuf[wv][64 + lane] = knn[nbase * 16 + 64 + lane];

    float s[8], s2[8];
#pragma unroll
    for (int m = 0; m < 8; m++) { s[m] = 0.f; s2[m] = 0.f; }

    int j0 = ibuf[wv][k8], j1 = ibuf[wv][k8 + 8];
    float4 r0c = ((const float4*)(xkh + (size_t)j0 * 64))[ch];
    float4 r1c = ((const float4*)(xkh + (size_t)j1 * 64))[ch];
    float4 qc  = ((const float4*)(xqh + (size_t)nbase * 64))[ch];

#pragma unroll
    for (int n = 0; n < 8; n++) {
        float4 r0n = {}, r1n = {}, qn = {};
        if (n < 7) {
            int ja = ibuf[wv][(n + 1) * 16 + k8], jb = ibuf[wv][(n + 1) * 16 + k8 + 8];
            r0n = ((const float4*)(xkh + (size_t)ja * 64))[ch];
            r1n = ((const float4*)(xkh + (size_t)jb * 64))[ch];
            qn  = ((const float4*)(xqh + (size_t)(nbase + n + 1) * 64))[ch];
        }
        float qv[8], u[8];
        cvt8(qc, qv);
        cvt8(r0c, u);
#pragma unroll
        for (int m = 0; m < 8; m++) { float w = u[m] - qv[m]; s[m] += w; s2[m] += w * w; }
        cvt8(r1c, u);
#pragma unroll
        for (int m = 0; m < 8; m++) { float w = u[m] - qv[m]; s[m] += w; s2[m] += w * w; }
        r0c = r0n; r1c = r1n; qc = qn;
    }
#pragma unroll
    for (int off = 8; off <= 32; off <<= 1)
#pragma unroll
        for (int m = 0; m < 8; m++) {
            s[m] += __shfl_xor(s[m], off);
            s2[m] += __shfl_xor(s2[m], off);
        }
    if (k8 == 0) {
#pragma unroll
        for (int m = 0; m < 8; m++) {
            red[wv][ch * 8 + m] = s[m];
            red[wv][64 + ch * 8 + m] = s2[m];
        }
    }
    __syncthreads();
    if (threadIdx.x < 128) {
        float t = red[0][threadIdx.x] + red[1][threadIdx.x] +
                  red[2][threadIdx.x] + red[3][threadIdx.x];
        atomicAdd(&st0[threadIdx.x], t);
    }
}

// ---------------------------------------------------------------------------
// wmlp1 via MFMA (r10-verified) + fused w1 stats (lane holds single d=m16).
// ---------------------------------------------------------------------------
__global__ __launch_bounds__(256) void wmlp1_k(const __half* __restrict__ xqh,
                                               const __half* __restrict__ xkh,
                                               const int* __restrict__ knn,
                                               const float* __restrict__ st0,
                                               const float* __restrict__ gw0,
                                               const float* __restrict__ bw0,
                                               const float* __restrict__ Ww1,
                                               __half* __restrict__ w1bh,
                                               float* __restrict__ stw1)
{
    __shared__ int ibuf[4][128];
    const int lane = threadIdx.x & 63, wv = threadIdx.x >> 6;
    const int m16 = lane & 15;          // neighbor index (A row)
    const int q = lane >> 4;            // channel quad
    const int nbase = blockIdx.x * 32 + wv * 8;
    const float cinv = 1.f / (float)(N1 * KNN);

    ibuf[wv][lane] = knn[nbase * 16 + lane];
    ibuf[wv][64 + lane] = knn[nbase * 16 + 64 + lane];

    __half2 sc2a[4], sh2a[4], sc2b[4], sh2b[4];
#pragma unroll
    for (int t = 0; t < 4; t++) {
        int c0 = q * 8 + 2 * t;
        int c1 = 32 + q * 8 + 2 * t;
        float m0 = st0[c0] * cinv, m0b = st0[c0 + 1] * cinv;
        float v0 = st0[64 + c0] * cinv - m0 * m0;
        float v0b = st0[64 + c0 + 1] * cinv - m0b * m0b;
        float sg0 = gw0[c0] * rsqrtf(v0 + EPS);
        float sg0b = gw0[c0 + 1] * rsqrtf(v0b + EPS);
        sc2a[t] = __floats2half2_rn(sg0, sg0b);
        sh2a[t] = __floats2half2_rn(bw0[c0] - m0 * sg0, bw0[c0 + 1] - m0b * sg0b);
        float m1 = st0[c1] * cinv, m1b = st0[c1 + 1] * cinv;
        float v1 = st0[64 + c1] * cinv - m1 * m1;
        float v1b = st0[64 + c1 + 1] * cinv - m1b * m1b;
        float sg1 = gw0[c1] * rsqrtf(v1 + EPS);
        float sg1b = gw0[c1 + 1] * rsqrtf(v1b + EPS);
        sc2b[t] = __floats2half2_rn(sg1, sg1b);
        sh2b[t] = __floats2half2_rn(bw0[c1] - m1 * sg1, bw0[c1 + 1] - m1b * sg1b);
    }
    const int nc = m16 < 8 ? m16 : 7;
    H8V b0, b1;
#pragma unroll
    for (int j = 0; j < 8; j += 2) {
        b0.h2[j / 2] = __floats2half2_rn(Ww1[(q * 8 + j) * 8 + nc],
                                         Ww1[(q * 8 + j + 1) * 8 + nc]);
        b1.h2[j / 2] = __floats2half2_rn(Ww1[(32 + q * 8 + j) * 8 + nc],
                                         Ww1[(32 + q * 8 + j + 1) * 8 + nc]);
    }

    int jc = ibuf[wv][m16];
    float4 a0c = *(const float4*)(xkh + (size_t)jc * 64 + q * 8);
    float4 a1c = *(const float4*)(xkh + (size_t)jc * 64 + 32 + q * 8);
    float4 q0c = *(const float4*)(xqh + (size_t)nbase * 64 + q * 8);
    float4 q1c = *(const float4*)(xqh + (size_t)nbase * 64 + 32 + q * 8);

    float sacc = 0.f, s2acc = 0.f;

#pragma unroll
    for (int n = 0; n < 8; n++) {
        const int i = nbase + n;
        float4 a0n = {}, a1n = {}, q0n = {}, q1n = {};
        if (n < 7) {
            int jn = ibuf[wv][(n + 1) * 16 + m16];
            a0n = *(const float4*)(xkh + (size_t)jn * 64 + q * 8);
            a1n = *(const float4*)(xkh + (size_t)jn * 64 + 32 + q * 8);
            q0n = *(const float4*)(xqh + (size_t)(i + 1) * 64 + q * 8);
            q1n = *(const float4*)(xqh + (size_t)(i + 1) * 64 + 32 + q * 8);
        }
        F4H8 ua, ub, qa, qb;
        ua.f4 = a0c; ub.f4 = a1c; qa.f4 = q0c; qb.f4 = q1c;
        H8V ta, tb;
#pragma unroll
        for (int t = 0; t < 4; t++) {
            __half2 qsh = __hsub2(sh2a[t], __hmul2(qa.h2[t], sc2a[t]));
            ta.h2[t] = relu2(__hfma2(ua.h2[t], sc2a[t], qsh));
            __half2 qsh2 = __hsub2(sh2b[t], __hmul2(qb.h2[t], sc2b[t]));
            tb.h2[t] = relu2(__hfma2(ub.h2[t], sc2b[t], qsh2));
        }
        f32x4 acc = {0.f, 0.f, 0.f, 0.f};
        acc = __builtin_amdgcn_mfma_f32_16x16x32_f16(ta.v, b0.v, acc, 0, 0, 0);
        acc = __builtin_amdgcn_mfma_f32_16x16x32_f16(tb.v, b1.v, acc, 0, 0, 0);

        if (m16 < 8) {
#pragma unroll
            for (int r = 0; r < 4; r++) {
                float v = acc[r];
                sacc += v; s2acc += v * v;
                w1bh[((size_t)i * 16 + q * 4 + r) * 8 + m16] = __float2half_rn(v);
            }
        }
        a0c = a0n; a1c = a1n; q0c = q0n; q1c = q1n;
    }
    // fold w1 stats: sum over q lanes (xor 16, 32 keep m16 fixed)
    sacc += __shfl_xor(sacc, 16);  s2acc += __shfl_xor(s2acc, 16);
    sacc += __shfl_xor(sacc, 32);  s2acc += __shfl_xor(s2acc, 32);
    if (q == 0 && m16 < 8) {
        atomicAdd(&stw1[m16], sacc);
        atomicAdd(&stw1[8 + m16], s2acc);
    }
}

// ---------------------------------------------------------------------------
// attn: bn1+relu -> @Ww2 -> softmax over k -> weighted xvp agg -> + residual.
// lane=(k8,ch); 8 nodes/wave, depth-2 rolling prefetch. (r7 version)
// ---------------------------------------------------------------------------
__global__ __launch_bounds__(256) void attn_k(const __half* __restrict__ w1bh,
                                              const float* __restrict__ stw1,
                                              const float* __restrict__ gw1,
                                              const float* __restrict__ bew1,
                                              const float* __restrict__ Ww2,
                                              const int* __restrict__ knn,
                                              const __half* __restrict__ xvph,
                                              const float* __restrict__ y1,
                                              const float* __restrict__ st1,
                                              const float* __restrict__ g1,
                                              const float* __restrict__ be1,
                                              float* __restrict__ out)
{
    __shared__ int ibuf[4][128];
    __shared__ float rbuf[4][64];
    const int lane = threadIdx.x & 63, wv = threadIdx.x >> 6;
    const int k8 = lane >> 3, ch = lane & 7;
    const int nbase = blockIdx.x * 32 + wv * 8;
    const float cinv = 1.f / (float)(N1 * KNN);

    ibuf[wv][lane] = knn[nbase * 16 + lane];
    ibuf[wv][64 + lane] = knn[nbase * 16 + 64 + lane];

    float sc1[8], sh1[8];
#pragma unroll
    for (int e = 0; e < 8; e++) {
        float mean = stw1[e] * cinv;
        float var = stw1[8 + e] * cinv - mean * mean;
        float sg = gw1[e] * rsqrtf(var + EPS);
        sc1[e] = sg; sh1[e] = bew1[e] - mean * sg;
    }
    float w2c[8];
#pragma unroll
    for (int e = 0; e < 8; e++) w2c[e] = Ww2[e * 8 + ch];

    float meanr = st1[lane] * (1.f / N1);
    float varr = st1[64 + lane] * (1.f / N1) - meanr * meanr;
    float sgr = g1[lane] * rsqrtf(varr + EPS);
    float shr = be1[lane] - meanr * sgr;

    int j0 = ibuf[wv][k8], j1 = ibuf[wv][k8 + 8];
    float4 v0c = ((const float4*)(xvph + (size_t)j0 * 64))[ch];
    float4 v1c = ((const float4*)(xvph + (size_t)j1 * 64))[ch];
    float4 w0c = *(const float4*)(w1bh + ((size_t)nbase * 16 + k8) * 8);
    float4 w1c = *(const float4*)(w1bh + ((size_t)nbase * 16 + k8 + 8) * 8);
    float yc = y1[(size_t)nbase * 64 + lane];

#pragma unroll
    for (int n = 0; n < 8; n++) {
        const int i = nbase + n;
        float4 v0n = {}, v1n = {}, w0n = {}, w1n = {};
        float yn = 0.f;
        if (n < 7) {
            int ja = ibuf[wv][(n + 1) * 16 + k8], jb = ibuf[wv][(n + 1) * 16 + k8 + 8];
            v0n = ((const float4*)(xvph + (size_t)ja * 64))[ch];
            v1n = ((const float4*)(xvph + (size_t)jb * 64))[ch];
            w0n = *(const float4*)(w1bh + ((size_t)(i + 1) * 16 + k8) * 8);
            w1n = *(const float4*)(w1bh + ((size_t)(i + 1) * 16 + k8 + 8) * 8);
            yn = y1[(size_t)(i + 1) * 64 + lane];
        }
        float w1v[8];
        cvt8(w0c, w1v);
        float a0 = 0.f;
#pragma unroll
        for (int e = 0; e < 8; e++)
            a0 += fmaxf(w1v[e] * sc1[e] + sh1[e], 0.f) * w2c[e];
        cvt8(w1c, w1v);
        float a1 = 0.f;
#pragma unroll
        for (int e = 0; e < 8; e++)
            a1 += fmaxf(w1v[e] * sc1[e] + sh1[e], 0.f) * w2c[e];

        float mx = fmaxf(a0, a1);
#pragma unroll
        for (int off = 8; off <= 32; off <<= 1) mx = fmaxf(mx, __shfl_xor(mx, off));
        float e0 = __expf(a0 - mx), e1 = __expf(a1 - mx);
        float sum = e0 + e1;
#pragma unroll
        for (int off = 8; off <= 32; off <<= 1) sum += __shfl_xor(sum, off);
        float inv = 1.f / sum;
        float wg0 = e0 * inv, wg1 = e1 * inv;

        float v[8], acc[8];
        cvt8(v0c, v);
#pragma unroll
        for (int s = 0; s < 8; s++) acc[s] = wg0 * v[s];
        cvt8(v1c, v);
#pragma unroll
        for (int s = 0; s < 8; s++) acc[s] += wg1 * v[s];
#pragma unroll
        for (int off = 8; off <= 32; off <<= 1)
#pragma unroll
            for (int s = 0; s < 8; s++) acc[s] += __shfl_xor(acc[s], off);

        if (k8 == 0) {
#pragma unroll
            for (int s = 0; s < 8; s++) rbuf[wv][s * 8 + ch] = acc[s];
        }
        float xh = fmaxf(yc * sgr + shr, 0.f);
        out[(size_t)i * 64 + lane] = xh + rbuf[wv][lane];

        v0c = v0n; v1c = v1n; w0c = w0n; w1c = w1n; yc = yn;
    }
}

// ---------------------------------------------------------------------------
extern "C" void kernel_launch(void* const* d_in, const int* in_sizes, int n_in,
                              void* d_out, int out_size, void* d_ws, size_t ws_size,
                              hipStream_t stream)
{
    const float* p1   = (const float*)d_in[0];
    const float* x1   = (const float*)d_in[1];
    const float* p2   = (const float*)d_in[2];
    const float* x2   = (const float*)d_in[3];
    const int*   knn  = (const int*)d_in[4];
    const int*   iidx = (const int*)d_in[5];
    const float* W1   = (const float*)d_in[6];
    const float* g1   = (const float*)d_in[8];
    const float* be1  = (const float*)d_in[9];
    const float* W2   = (const float*)d_in[10];
    const float* g2   = (const float*)d_in[12];
    const float* be2  = (const float*)d_in[13];
    const float* Wq   = (const float*)d_in[14];
    const float* bq   = (const float*)d_in[15];
    const float* Wk   = (const float*)d_in[16];
    const float* Wv   = (const float*)d_in[18];
    const float* bv   = (const float*)d_in[19];
    const float* gw0  = (const float*)d_in[20];
    const float* bw0  = (const float*)d_in[21];
    const float* Ww1  = (const float*)d_in[22];
    const float* gw1  = (const float*)d_in[24];
    const float* bew1 = (const float*)d_in[25];
    const float* Ww2  = (const float*)d_in[26];
    // b1, b2, bk, bw1, bw2 provably cancel (BN mean-subtraction / softmax shift)

    float* ws   = (float*)d_ws;
    float* y1   = ws + OFF_Y1;
    float* y2   = ws + OFF_Y2;
    __half* xqh  = (__half*)(ws + OFF_XQH);
    __half* xkh  = (__half*)(ws + OFF_XKH);
    __half* xvph = (__half*)(ws + OFF_XVPH);
    __half* w1bh = (__half*)(ws + OFF_W1BH);
    float* st1  = ws + OFF_ST;
    float* st2  = st1 + 128;
    float* st0  = st1 + 256;
    float* stw1 = st1 + 384;
    float* outp = (float*)d_out;

    hipMemsetAsync(st1, 0, 512 * sizeof(float), stream);

    stats12_k<<<197, 256, 0, stream>>>(x1, W1, x2, W2, y1, y2, st1, st2);
    qkv_k<<<782, 256, 0, stream>>>(y1, st1, g1, be1, Wq, bq,
                                   p1, p2, iidx, y2, st2, g2, be2,
                                   Wk, Wv, bv, xqh, xkh, xvph);
    wstats_k<<<1250, 256, 0, stream>>>(xqh, xkh, knn, st0);
    wmlp1_k<<<1250, 256, 0, stream>>>(xqh, xkh, knn, st0, gw0, bw0, Ww1, w1bh, stw1);
    attn_k<<<1250, 256, 0, stream>>>(w1bh, stw1, gw1, bew1, Ww2, knn, xvph,
                                     y1, st1, g1, be1, outp);
}

// Round 13
// 243.270 us; speedup vs baseline: 1.4592x; 1.4592x over previous
//
#include <hip/hip_runtime.h>
#include <hip/hip_fp16.h>
#include <cstdint>
#include <cstddef>

static constexpr int N1 = 40000;
static constexpr int N2 = 10000;
static constexpr int KNN = 16;
static constexpr float EPS = 1e-5f;

// Workspace layout (float offsets; fp16 regions reinterpret the same slots)
static constexpr size_t OFF_Y1   = 0;          // N1*64 f32 raw linear1 output
static constexpr size_t OFF_Y2   = 2560000;    // N2*64 f32 raw linear2 output
static constexpr size_t OFF_XQH  = 5760000;    // N1*64 __half
static constexpr size_t OFF_XKH  = 8320000;    // N1*64 __half
static constexpr size_t OFF_XVPH = 10880000;   // N1*64 __half (PERMUTED [j][d*8+s])
static constexpr size_t OFF_W1BH = 13440000;   // N1*16*8 __half
static constexpr size_t OFF_ST   = 18560000;   // st1(128) st2(128) st0(128) stw1(16)

union F4H8 { float4 f4; __half2 h2[4]; };

typedef _Float16 f16x8 __attribute__((ext_vector_type(8)));
typedef float f32x4 __attribute__((ext_vector_type(4)));
union H8V { __half2 h2[4]; f16x8 v; };

__device__ __forceinline__ void cvt8(float4 raw, float* u) {
    F4H8 c; c.f4 = raw;
#pragma unroll
    for (int t = 0; t < 4; t++) {
        float2 f = __half22float2(c.h2[t]);
        u[2 * t] = f.x; u[2 * t + 1] = f.y;
    }
}

// packed relu: per-component max with 0
__device__ __forceinline__ __half2 relu2(__half2 a) {
    const __half z = __float2half_rn(0.f);
    __half2 r;
    r.x = __hmax(a.x, z);
    r.y = __hmax(a.y, z);
    return r;
}

// ---------------------------------------------------------------------------
// MFMA GEMM + column stats (r11-verified): Y = fp16(X) @ fp16(W), f32 acc.
// ---------------------------------------------------------------------------
template<int CIN>
__device__ __forceinline__ void gemm_mfma_stats_body(const float* __restrict__ X,
                                                     float* __restrict__ Y,
                                                     float* __restrict__ stats,
                                                     int rowbase, int nrows,
                                                     const float* __restrict__ Wsm)
{
    constexpr int KC = CIN / 32;
    const int lane = threadIdx.x & 63, wv = threadIdx.x >> 6;
    const int c16 = lane & 15, q = lane >> 4;

    H8V b[4][KC];
#pragma unroll
    for (int g = 0; g < 4; g++)
#pragma unroll
        for (int h = 0; h < KC; h++)
#pragma unroll
            for (int j = 0; j < 8; j += 2) {
                int k0 = h * 32 + q * 8 + j;
                b[g][h].h2[j / 2] = __floats2half2_rn(Wsm[k0 * 64 + g * 16 + c16],
                                                      Wsm[(k0 + 1) * 64 + g * 16 + c16]);
            }

    float sA[4] = {0.f, 0.f, 0.f, 0.f}, sQ[4] = {0.f, 0.f, 0.f, 0.f};

#pragma unroll
    for (int it = 0; it < 4; it++) {
        const int r0 = wv * 64 + it * 16;
        const bool valid = (r0 + c16) < nrows;
        const int grow = rowbase + r0 + c16;
        H8V a[KC];
#pragma unroll
        for (int h = 0; h < KC; h++) {
            float4 xa = make_float4(0.f, 0.f, 0.f, 0.f);
            float4 xb = make_float4(0.f, 0.f, 0.f, 0.f);
            if (valid) {
                xa = *(const float4*)(X + (size_t)grow * CIN + h * 32 + q * 8);
                xb = *(const float4*)(X + (size_t)grow * CIN + h * 32 + q * 8 + 4);
            }
            a[h].h2[0] = __floats2half2_rn(xa.x, xa.y);
            a[h].h2[1] = __floats2half2_rn(xa.z, xa.w);
            a[h].h2[2] = __floats2half2_rn(xb.x, xb.y);
            a[h].h2[3] = __floats2half2_rn(xb.z, xb.w);
        }
        f32x4 acc[4];
#pragma unroll
        for (int g = 0; g < 4; g++) acc[g] = (f32x4){0.f, 0.f, 0.f, 0.f};
#pragma unroll
        for (int h = 0; h < KC; h++)
#pragma unroll
            for (int g = 0; g < 4; g++)
                acc[g] = __builtin_amdgcn_mfma_f32_16x16x32_f16(a[h].v, b[g][h].v,
                                                                acc[g], 0, 0, 0);
#pragma unroll
        for (int g = 0; g < 4; g++)
#pragma unroll
            for (int r = 0; r < 4; r++) {
                int rr = r0 + q * 4 + r;
                if (rr < nrows)
                    Y[(size_t)(rowbase + rr) * 64 + g * 16 + c16] = acc[g][r];
                sA[g] += acc[g][r];
                sQ[g] += acc[g][r] * acc[g][r];
            }
    }
#pragma unroll
    for (int off = 16; off <= 32; off <<= 1)
#pragma unroll
        for (int g = 0; g < 4; g++) {
            sA[g] += __shfl_xor(sA[g], off);
            sQ[g] += __shfl_xor(sQ[g], off);
        }
    if (q == 0) {
#pragma unroll
        for (int g = 0; g < 4; g++) {
            atomicAdd(&stats[g * 16 + c16], sA[g]);
            atomicAdd(&stats[64 + g * 16 + c16], sQ[g]);
        }
    }
}

__global__ __launch_bounds__(256) void stats12_k(const float* __restrict__ x1,
                                                 const float* __restrict__ W1,
                                                 const float* __restrict__ x2,
                                                 const float* __restrict__ W2,
                                                 float* __restrict__ y1,
                                                 float* __restrict__ y2,
                                                 float* __restrict__ st1,
                                                 float* __restrict__ st2)
{
    __shared__ float Wsm[128 * 64];
    if (blockIdx.x < 157) {
        for (int t = threadIdx.x; t < 64 * 64; t += 256) Wsm[t] = W1[t];
        __syncthreads();
        int rowbase = blockIdx.x * 256;
        gemm_mfma_stats_body<64>(x1, y1, st1, rowbase, N1 - rowbase, Wsm);
    } else {
        for (int t = threadIdx.x; t < 128 * 64; t += 256) Wsm[t] = W2[t];
        __syncthreads();
        int rowbase = (blockIdx.x - 157) * 256;
        gemm_mfma_stats_body<128>(x2, y2, st2, rowbase, N2 - rowbase, Wsm);
    }
}

// ---------------------------------------------------------------------------
// qkv (MFMA, r12): blocks [0,157): xqh = fp16(relu(bn1(y1)) @ Wq + bq)
//                  blocks [157,782): interp -> Xs; xkh / xvph via MFMA
// ---------------------------------------------------------------------------
__global__ __launch_bounds__(256) void qkv_k(const float* __restrict__ y1,
                                             const float* __restrict__ st1,
                                             const float* __restrict__ g1,
                                             const float* __restrict__ be1,
                                             const float* __restrict__ Wq,
                                             const float* __restrict__ bq,
                                             const float* __restrict__ p1,
                                             const float* __restrict__ p2,
                                             const int* __restrict__ iidx,
                                             const float* __restrict__ y2,
                                             const float* __restrict__ st2,
                                             const float* __restrict__ g2,
                                             const float* __restrict__ be2,
                                             const float* __restrict__ Wk_,
                                             const float* __restrict__ Wv_,
                                             const float* __restrict__ bv_,
                                             __half* __restrict__ xqh,
                                             __half* __restrict__ xkh,
                                             __half* __restrict__ xvph)
{
    __shared__ float sm[12672];
    const int lane = threadIdx.x & 63, wv = threadIdx.x >> 6;
    const int c16 = lane & 15, q = lane >> 4;

    if (blockIdx.x < 157) {
        float* Ws = sm;                 // 4096
        float* cst = sm + 4096;         // 128
        for (int t = threadIdx.x; t < 4096; t += 256) Ws[t] = Wq[t];
        if (threadIdx.x < 64) {
            int c = threadIdx.x;
            float mean = st1[c] * (1.f / N1);
            float var = st1[64 + c] * (1.f / N1) - mean * mean;
            float sg = g1[c] * rsqrtf(var + EPS);
            cst[c] = sg; cst[64 + c] = be1[c] - mean * sg;
        }
        __syncthreads();

        H8V b[4][2];
#pragma unroll
        for (int g = 0; g < 4; g++)
#pragma unroll
            for (int h = 0; h < 2; h++)
#pragma unroll
                for (int j = 0; j < 8; j += 2) {
                    int k0 = h * 32 + q * 8 + j;
                    b[g][h].h2[j / 2] = __floats2half2_rn(Ws[k0 * 64 + g * 16 + c16],
                                                          Ws[(k0 + 1) * 64 + g * 16 + c16]);
                }
        float scq[16], shq[16];
#pragma unroll
        for (int h = 0; h < 2; h++)
#pragma unroll
            for (int j = 0; j < 8; j++) {
                int c = h * 32 + q * 8 + j;
                scq[h * 8 + j] = cst[c]; shq[h * 8 + j] = cst[64 + c];
            }
        float bqv[4];
#pragma unroll
        for (int g = 0; g < 4; g++) bqv[g] = bq[g * 16 + c16];

        const int rowbase = blockIdx.x * 256;
        const int nrows = N1 - rowbase;
#pragma unroll
        for (int it = 0; it < 4; it++) {
            const int r0 = wv * 64 + it * 16;
            const bool valid = (r0 + c16) < nrows;
            const int grow = rowbase + r0 + c16;
            H8V a[2];
#pragma unroll
            for (int h = 0; h < 2; h++) {
                float u[8];
#pragma unroll
                for (int j = 0; j < 8; j++) u[j] = 0.f;
                if (valid) {
                    float4 xa = *(const float4*)(y1 + (size_t)grow * 64 + h * 32 + q * 8);
                    float4 xb = *(const float4*)(y1 + (size_t)grow * 64 + h * 32 + q * 8 + 4);
                    u[0] = xa.x; u[1] = xa.y; u[2] = xa.z; u[3] = xa.w;
                    u[4] = xb.x; u[5] = xb.y; u[6] = xb.z; u[7] = xb.w;
#pragma unroll
                    for (int j = 0; j < 8; j++)
                        u[j] = fmaxf(u[j] * scq[h * 8 + j] + shq[h * 8 + j], 0.f);
                }
#pragma unroll
                for (int t = 0; t < 4; t++)
                    a[h].h2[t] = __floats2half2_rn(u[2 * t], u[2 * t + 1]);
            }
            f32x4 acc[4];
#pragma unroll
            for (int g = 0; g < 4; g++) acc[g] = (f32x4){0.f, 0.f, 0.f, 0.f};
#pragma unroll
            for (int h = 0; h < 2; h++)
#pragma unroll
                for (int g = 0; g < 4; g++)
                    acc[g] = __builtin_amdgcn_mfma_f32_16x16x32_f16(a[h].v, b[g][h].v,
                                                                    acc[g], 0, 0, 0);
#pragma unroll
            for (int g = 0; g < 4; g++)
#pragma unroll
                for (int r = 0; r < 4; r++) {
                    int rr = r0 + q * 4 + r;
                    if (rr < nrows)
                        xqh[(size_t)(rowbase + rr) * 64 + g * 16 + c16] =
                            __float2half_rn(acc[g][r] + bqv[g]);
                }
        }
    } else {
        float* Wks = sm;                // 4096
        float* Wvs = sm + 4096;         // 4096
        float* Xs = sm + 8192;          // 64 x 68 -> ends 12544
        float* cst = sm + 12544;        // 128
        for (int t = threadIdx.x; t < 4096; t += 256) { Wks[t] = Wk_[t]; Wvs[t] = Wv_[t]; }
        if (threadIdx.x < 64) {
            int c = threadIdx.x;
            float mean = st2[c] * (1.f / N2);
            float var = st2[64 + c] * (1.f / N2) - mean * mean;
            float sg = g2[c] * rsqrtf(var + EPS);
            cst[c] = sg; cst[64 + c] = be2[c] - mean * sg;
        }
        __syncthreads();
        const int base = (blockIdx.x - 157) * 64;
        {   // interp fill: thread = (row, quarter)
            int row = threadIdx.x >> 2, q4 = threadIdx.x & 3;
            int gi = base + row;
            int j0 = iidx[gi * 3 + 0], j1 = iidx[gi * 3 + 1], j2 = iidx[gi * 3 + 2];
            float ax = p1[gi * 3 + 0], ay = p1[gi * 3 + 1], az = p1[gi * 3 + 2];
            float dx, dy, dz;
            dx = ax - p2[j0 * 3 + 0]; dy = ay - p2[j0 * 3 + 1]; dz = az - p2[j0 * 3 + 2];
            float w0 = 1.f / (sqrtf(dx * dx + dy * dy + dz * dz) + 1e-8f);
            dx = ax - p2[j1 * 3 + 0]; dy = ay - p2[j1 * 3 + 1]; dz = az - p2[j1 * 3 + 2];
            float w1 = 1.f / (sqrtf(dx * dx + dy * dy + dz * dz) + 1e-8f);
            dx = ax - p2[j2 * 3 + 0]; dy = ay - p2[j2 * 3 + 1]; dz = az - p2[j2 * 3 + 2];
            float w2 = 1.f / (sqrtf(dx * dx + dy * dy + dz * dz) + 1e-8f);
            float inv = 1.f / (w0 + w1 + w2);
            w0 *= inv; w1 *= inv; w2 *= inv;
#pragma unroll
            for (int c4 = 0; c4 < 4; c4++) {
                int col = q4 * 16 + c4 * 4;
                float4 a = *(const float4*)(y2 + (size_t)j0 * 64 + col);
                float4 b = *(const float4*)(y2 + (size_t)j1 * 64 + col);
                float4 c = *(const float4*)(y2 + (size_t)j2 * 64 + col);
                float4 o;
                o.x = w0 * fmaxf(a.x * cst[col] + cst[64 + col], 0.f)
                    + w1 * fmaxf(b.x * cst[col] + cst[64 + col], 0.f)
                    + w2 * fmaxf(c.x * cst[col] + cst[64 + col], 0.f);
                o.y = w0 * fmaxf(a.y * cst[col + 1] + cst[64 + col + 1], 0.f)
                    + w1 * fmaxf(b.y * cst[col + 1] + cst[64 + col + 1], 0.f)
                    + w2 * fmaxf(c.y * cst[col + 1] + cst[64 + col + 1], 0.f);
                o.z = w0 * fmaxf(a.z * cst[col + 2] + cst[64 + col + 2], 0.f)
                    + w1 * fmaxf(b.z * cst[col + 2] + cst[64 + col + 2], 0.f)
                    + w2 * fmaxf(c.z * cst[col + 2] + cst[64 + col + 2], 0.f);
                o.w = w0 * fmaxf(a.w * cst[col + 3] + cst[64 + col + 3], 0.f)
                    + w1 * fmaxf(b.w * cst[col + 3] + cst[64 + col + 3], 0.f)
                    + w2 * fmaxf(c.w * cst[col + 3] + cst[64 + col + 3], 0.f);
                *(float4*)(Xs + row * 68 + col) = o;
            }
        }
        __syncthreads();

        H8V bk[4][2], bvv[4][2];
#pragma unroll
        for (int g = 0; g < 4; g++)
#pragma unroll
            for (int h = 0; h < 2; h++)
#pragma unroll
                for (int j = 0; j < 8; j += 2) {
                    int k0 = h * 32 + q * 8 + j;
                    bk[g][h].h2[j / 2] = __floats2half2_rn(Wks[k0 * 64 + g * 16 + c16],
                                                           Wks[(k0 + 1) * 64 + g * 16 + c16]);
                    bvv[g][h].h2[j / 2] = __floats2half2_rn(Wvs[k0 * 64 + g * 16 + c16],
                                                            Wvs[(k0 + 1) * 64 + g * 16 + c16]);
                }
        float bvb[4];
#pragma unroll
        for (int g = 0; g < 4; g++) bvb[g] = bv_[g * 16 + c16];

        H8V a[2];
#pragma unroll
        for (int h = 0; h < 2; h++) {
            const float* xp = Xs + (wv * 16 + c16) * 68 + h * 32 + q * 8;
            float4 xa = *(const float4*)xp;
            float4 xb = *(const float4*)(xp + 4);
            a[h].h2[0] = __floats2half2_rn(xa.x, xa.y);
            a[h].h2[1] = __floats2half2_rn(xa.z, xa.w);
            a[h].h2[2] = __floats2half2_rn(xb.x, xb.y);
            a[h].h2[3] = __floats2half2_rn(xb.z, xb.w);
        }
        f32x4 acck[4], accv[4];
#pragma unroll
        for (int g = 0; g < 4; g++) {
            acck[g] = (f32x4){0.f, 0.f, 0.f, 0.f};
            accv[g] = (f32x4){0.f, 0.f, 0.f, 0.f};
        }
#pragma unroll
        for (int h = 0; h < 2; h++)
#pragma unroll
            for (int g = 0; g < 4; g++) {
                acck[g] = __builtin_amdgcn_mfma_f32_16x16x32_f16(a[h].v, bk[g][h].v,
                                                                 acck[g], 0, 0, 0);
                accv[g] = __builtin_amdgcn_mfma_f32_16x16x32_f16(a[h].v, bvv[g][h].v,
                                                                 accv[g], 0, 0, 0);
            }
#pragma unroll
        for (int g = 0; g < 4; g++)
#pragma unroll
            for (int r = 0; r < 4; r++) {
                int grow = base + wv * 16 + q * 4 + r;
                xkh[(size_t)grow * 64 + g * 16 + c16] = __float2half_rn(acck[g][r]);
            }
        __syncthreads();                    // all LDS reads done
        __half* hb = (__half*)sm;           // 64 rows x 64 halves
#pragma unroll
        for (int g = 0; g < 4; g++)
#pragma unroll
            for (int r = 0; r < 4; r++) {
                int c = g * 16 + c16;
                int pc = (c & 7) * 8 + (c >> 3);
                hb[(wv * 16 + q * 4 + r) * 64 + pc] = __float2half_rn(accv[g][r] + bvb[g]);
            }
        __syncthreads();
        for (int f = threadIdx.x; f < 512; f += 256) {
            float4 v = *(const float4*)((const char*)hb + f * 16);
            ((float4*)(xvph + (size_t)base * 64))[f] = v;
        }
    }
}

// ---------------------------------------------------------------------------
// wstats: per-channel sum/sumsq of w = xk[knn]-xq. lane=(k8,ch);
// 8 nodes/wave, depth-2 rolling prefetch. grid = 1250. (r7 version)
// ---------------------------------------------------------------------------
__global__ __launch_bounds__(256) void wstats_k(const __half* __restrict__ xqh,
                                                const __half* __restrict__ xkh,
                                                const int* __restrict__ knn,
                                                float* __restrict__ st0)
{
    __shared__ int ibuf[4][128];
    __shared__ float red[4][128];
    const int lane = threadIdx.x & 63, wv = threadIdx.x >> 6;
    const int k8 = lane >> 3, ch = lane & 7;
    const int nbase = blockIdx.x * 32 + wv * 8;

    ibuf[wv][lane] = knn[nbase * 16 + lane];
    ibuf[wv][64 + lane] = knn[nbase * 16 + 64 + lane];

    float s[8], s2[8];
#pragma unroll
    for (int m = 0; m < 8; m++) { s[m] = 0.f; s2[m] = 0.f; }

    int j0 = ibuf[wv][k8], j1 = ibuf[wv][k8 + 8];
    float4 r0c = ((const float4*)(xkh + (size_t)j0 * 64))[ch];
    float4 r1c = ((const float4*)(xkh + (size_t)j1 * 64))[ch];
    float4 qc  = ((const float4*)(xqh + (size_t)nbase * 64))[ch];

#pragma unroll
    for (int n = 0; n < 8; n++) {
        float4 r0n = {}, r1n = {}, qn = {};
        if (n < 7) {
            int ja = ibuf[wv][(n + 1) * 16 + k8], jb = ibuf[wv][(n + 1) * 16 + k8 + 8];
            r0n = ((const float4*)(xkh + (size_t)ja * 64))[ch];
            r1n = ((const float4*)(xkh + (size_t)jb * 64))[ch];
            qn  = ((const float4*)(xqh + (size_t)(nbase + n + 1) * 64))[ch];
        }
        float qv[8], u[8];
        cvt8(qc, qv);
        cvt8(r0c, u);
#pragma unroll
        for (int m = 0; m < 8; m++) { float w = u[m] - qv[m]; s[m] += w; s2[m] += w * w; }
        cvt8(r1c, u);
#pragma unroll
        for (int m = 0; m < 8; m++) { float w = u[m] - qv[m]; s[m] += w; s2[m] += w * w; }
        r0c = r0n; r1c = r1n; qc = qn;
    }
#pragma unroll
    for (int off = 8; off <= 32; off <<= 1)
#pragma unroll
        for (int m = 0; m < 8; m++) {
            s[m] += __shfl_xor(s[m], off);
            s2[m] += __shfl_xor(s2[m], off);
        }
    if (k8 == 0) {
#pragma unroll
        for (int m = 0; m < 8; m++) {
            red[wv][ch * 8 + m] = s[m];
            red[wv][64 + ch * 8 + m] = s2[m];
        }
    }
    __syncthreads();
    if (threadIdx.x < 128) {
        float t = red[0][threadIdx.x] + red[1][threadIdx.x] +
                  red[2][threadIdx.x] + red[3][threadIdx.x];
        atomicAdd(&st0[threadIdx.x], t);
    }
}

// ---------------------------------------------------------------------------
// wmlp1 via MFMA — EXACT r10/r11 version (no fused stats; do not touch:
// adding epilogue state collapses VGPR alloc -> serialized prefetch, 4x slower)
// ---------------------------------------------------------------------------
__global__ __launch_bounds__(256) void wmlp1_k(const __half* __restrict__ xqh,
                                               const __half* __restrict__ xkh,
                                               const int* __restrict__ knn,
                                               const float* __restrict__ st0,
                                               const float* __restrict__ gw0,
                                               const float* __restrict__ bw0,
                                               const float* __restrict__ Ww1,
                                               __half* __restrict__ w1bh)
{
    __shared__ int ibuf[4][128];
    const int lane = threadIdx.x & 63, wv = threadIdx.x >> 6;
    const int m16 = lane & 15;          // neighbor index (A row)
    const int q = lane >> 4;            // channel quad
    const int nbase = blockIdx.x * 32 + wv * 8;
    const float cinv = 1.f / (float)(N1 * KNN);

    ibuf[wv][lane] = knn[nbase * 16 + lane];
    ibuf[wv][64 + lane] = knn[nbase * 16 + 64 + lane];

    __half2 sc2a[4], sh2a[4], sc2b[4], sh2b[4];
#pragma unroll
    for (int t = 0; t < 4; t++) {
        int c0 = q * 8 + 2 * t;
        int c1 = 32 + q * 8 + 2 * t;
        float m0 = st0[c0] * cinv, m0b = st0[c0 + 1] * cinv;
        float v0 = st0[64 + c0] * cinv - m0 * m0;
        float v0b = st0[64 + c0 + 1] * cinv - m0b * m0b;
        float sg0 = gw0[c0] * rsqrtf(v0 + EPS);
        float sg0b = gw0[c0 + 1] * rsqrtf(v0b + EPS);
        sc2a[t] = __floats2half2_rn(sg0, sg0b);
        sh2a[t] = __floats2half2_rn(bw0[c0] - m0 * sg0, bw0[c0 + 1] - m0b * sg0b);
        float m1 = st0[c1] * cinv, m1b = st0[c1 + 1] * cinv;
        float v1 = st0[64 + c1] * cinv - m1 * m1;
        float v1b = st0[64 + c1 + 1] * cinv - m1b * m1b;
        float sg1 = gw0[c1] * rsqrtf(v1 + EPS);
        float sg1b = gw0[c1 + 1] * rsqrtf(v1b + EPS);
        sc2b[t] = __floats2half2_rn(sg1, sg1b);
        sh2b[t] = __floats2half2_rn(bw0[c1] - m1 * sg1, bw0[c1 + 1] - m1b * sg1b);
    }
    const int nc = m16 < 8 ? m16 : 7;
    H8V b0, b1;
#pragma unroll
    for (int j = 0; j < 8; j += 2) {
        b0.h2[j / 2] = __floats2half2_rn(Ww1[(q * 8 + j) * 8 + nc],
                                         Ww1[(q * 8 + j + 1) * 8 + nc]);
        b1.h2[j / 2] = __floats2half2_rn(Ww1[(32 + q * 8 + j) * 8 + nc],
                                         Ww1[(32 + q * 8 + j + 1) * 8 + nc]);
    }

    int jc = ibuf[wv][m16];
    float4 a0c = *(const float4*)(xkh + (size_t)jc * 64 + q * 8);
    float4 a1c = *(const float4*)(xkh + (size_t)jc * 64 + 32 + q * 8);
    float4 q0c = *(const float4*)(xqh + (size_t)nbase * 64 + q * 8);
    float4 q1c = *(const float4*)(xqh + (size_t)nbase * 64 + 32 + q * 8);

#pragma unroll
    for (int n = 0; n < 8; n++) {
        const int i = nbase + n;
        float4 a0n = {}, a1n = {}, q0n = {}, q1n = {};
        if (n < 7) {
            int jn = ibuf[wv][(n + 1) * 16 + m16];
            a0n = *(const float4*)(xkh + (size_t)jn * 64 + q * 8);
            a1n = *(const float4*)(xkh + (size_t)jn * 64 + 32 + q * 8);
            q0n = *(const float4*)(xqh + (size_t)(i + 1) * 64 + q * 8);
            q1n = *(const float4*)(xqh + (size_t)(i + 1) * 64 + 32 + q * 8);
        }
        F4H8 ua, ub, qa, qb;
        ua.f4 = a0c; ub.f4 = a1c; qa.f4 = q0c; qb.f4 = q1c;
        H8V ta, tb;
#pragma unroll
        for (int t = 0; t < 4; t++) {
            __half2 qsh = __hsub2(sh2a[t], __hmul2(qa.h2[t], sc2a[t]));
            ta.h2[t] = relu2(__hfma2(ua.h2[t], sc2a[t], qsh));
            __half2 qsh2 = __hsub2(sh2b[t], __hmul2(qb.h2[t], sc2b[t]));
            tb.h2[t] = relu2(__hfma2(ub.h2[t], sc2b[t], qsh2));
        }
        f32x4 acc = {0.f, 0.f, 0.f, 0.f};
        acc = __builtin_amdgcn_mfma_f32_16x16x32_f16(ta.v, b0.v, acc, 0, 0, 0);
        acc = __builtin_amdgcn_mfma_f32_16x16x32_f16(tb.v, b1.v, acc, 0, 0, 0);

        if (m16 < 8) {
#pragma unroll
            for (int r = 0; r < 4; r++) {
                w1bh[((size_t)i * 16 + q * 4 + r) * 8 + m16] = __float2half_rn(acc[r]);
            }
        }
        a0c = a0n; a1c = a1n; q0c = q0n; q1c = q1n;
    }
}

// ---------------------------------------------------------------------------
// Streaming stats of w1bh (sum/sumsq per d) -> stw1[16]
// ---------------------------------------------------------------------------
__global__ __launch_bounds__(256) void w1stats_k(const __half* __restrict__ w1bh,
                                                 float* __restrict__ stw1)
{
    float s[8], s2[8];
#pragma unroll
    for (int d = 0; d < 8; d++) { s[d] = 0.f; s2[d] = 0.f; }
    for (size_t r = blockIdx.x * 256 + threadIdx.x; r < (size_t)N1 * KNN;
         r += (size_t)gridDim.x * 256) {
        float4 raw = *(const float4*)(w1bh + r * 8);
        float u[8];
        cvt8(raw, u);
#pragma unroll
        for (int d = 0; d < 8; d++) { s[d] += u[d]; s2[d] += u[d] * u[d]; }
    }
#pragma unroll
    for (int off = 1; off <= 32; off <<= 1)
#pragma unroll
        for (int d = 0; d < 8; d++) {
            s[d] += __shfl_xor(s[d], off);
            s2[d] += __shfl_xor(s2[d], off);
        }
    __shared__ float red[4][16];
    const int lane = threadIdx.x & 63, wv = threadIdx.x >> 6;
    if (lane == 0) {
#pragma unroll
        for (int d = 0; d < 8; d++) { red[wv][d] = s[d]; red[wv][8 + d] = s2[d]; }
    }
    __syncthreads();
    if (threadIdx.x < 16) {
        float t = red[0][threadIdx.x] + red[1][threadIdx.x] +
                  red[2][threadIdx.x] + red[3][threadIdx.x];
        atomicAdd(&stw1[threadIdx.x], t);
    }
}

// ---------------------------------------------------------------------------
// attn: bn1+relu -> @Ww2 -> softmax over k -> weighted xvp agg -> + residual.
// lane=(k8,ch); 8 nodes/wave, depth-2 rolling prefetch. (r7 version)
// ---------------------------------------------------------------------------
__global__ __launch_bounds__(256) void attn_k(const __half* __restrict__ w1bh,
                                              const float* __restrict__ stw1,
                                              const float* __restrict__ gw1,
                                              const float* __restrict__ bew1,
                                              const float* __restrict__ Ww2,
                                              const int* __restrict__ knn,
                                              const __half* __restrict__ xvph,
                                              const float* __restrict__ y1,
                                              const float* __restrict__ st1,
                                              const float* __restrict__ g1,
                                              const float* __restrict__ be1,
                                              float* __restrict__ out)
{
    __shared__ int ibuf[4][128];
    __shared__ float rbuf[4][64];
    const int lane = threadIdx.x & 63, wv = threadIdx.x >> 6;
    const int k8 = lane >> 3, ch = lane & 7;
    const int nbase = blockIdx.x * 32 + wv * 8;
    const float cinv = 1.f / (float)(N1 * KNN);

    ibuf[wv][lane] = knn[nbase * 16 + lane];
    ibuf[wv][64 + lane] = knn[nbase * 16 + 64 + lane];

    float sc1[8], sh1[8];
#pragma unroll
    for (int e = 0; e < 8; e++) {
        float mean = stw1[e] * cinv;
        float var = stw1[8 + e] * cinv - mean * mean;
        float sg = gw1[e] * rsqrtf(var + EPS);
        sc1[e] = sg; sh1[e] = bew1[e] - mean * sg;
    }
    float w2c[8];
#pragma unroll
    for (int e = 0; e < 8; e++) w2c[e] = Ww2[e * 8 + ch];

    float meanr = st1[lane] * (1.f / N1);
    float varr = st1[64 + lane] * (1.f / N1) - meanr * meanr;
    float sgr = g1[lane] * rsqrtf(varr + EPS);
    float shr = be1[lane] - meanr * sgr;

    int j0 = ibuf[wv][k8], j1 = ibuf[wv][k8 + 8];
    float4 v0c = ((const float4*)(xvph + (size_t)j0 * 64))[ch];
    float4 v1c = ((const float4*)(xvph + (size_t)j1 * 64))[ch];
    float4 w0c = *(const float4*)(w1bh + ((size_t)nbase * 16 + k8) * 8);
    float4 w1c = *(const float4*)(w1bh + ((size_t)nbase * 16 + k8 + 8) * 8);
    float yc = y1[(size_t)nbase * 64 + lane];

#pragma unroll
    for (int n = 0; n < 8; n++) {
        const int i = nbase + n;
        float4 v0n = {}, v1n = {}, w0n = {}, w1n = {};
        float yn = 0.f;
        if (n < 7) {
            int ja = ibuf[wv][(n + 1) * 16 + k8], jb = ibuf[wv][(n + 1) * 16 + k8 + 8];
            v0n = ((const float4*)(xvph + (size_t)ja * 64))[ch];
            v1n = ((const float4*)(xvph + (size_t)jb * 64))[ch];
            w0n = *(const float4*)(w1bh + ((size_t)(i + 1) * 16 + k8) * 8);
            w1n = *(const float4*)(w1bh + ((size_t)(i + 1) * 16 + k8 + 8) * 8);
            yn = y1[(size_t)(i + 1) * 64 + lane];
        }
        float w1v[8];
        cvt8(w0c, w1v);
        float a0 = 0.f;
#pragma unroll
        for (int e = 0; e < 8; e++)
            a0 += fmaxf(w1v[e] * sc1[e] + sh1[e], 0.f) * w2c[e];
        cvt8(w1c, w1v);
        float a1 = 0.f;
#pragma unroll
        for (int e = 0; e < 8; e++)
            a1 += fmaxf(w1v[e] * sc1[e] + sh1[e], 0.f) * w2c[e];

        float mx = fmaxf(a0, a1);
#pragma unroll
        for (int off = 8; off <= 32; off <<= 1) mx = fmaxf(mx, __shfl_xor(mx, off));
        float e0 = __expf(a0 - mx), e1 = __expf(a1 - mx);
        float sum = e0 + e1;
#pragma unroll
        for (int off = 8; off <= 32; off <<= 1) sum += __shfl_xor(sum, off);
        float inv = 1.f / sum;
        float wg0 = e0 * inv, wg1 = e1 * inv;

        float v[8], acc[8];
        cvt8(v0c, v);
#pragma unroll
        for (int s = 0; s < 8; s++) acc[s] = wg0 * v[s];
        cvt8(v1c, v);
#pragma unroll
        for (int s = 0; s < 8; s++) acc[s] += wg1 * v[s];
#pragma unroll
        for (int off = 8; off <= 32; off <<= 1)
#pragma unroll
            for (int s = 0; s < 8; s++) acc[s] += __shfl_xor(acc[s], off);

        if (k8 == 0) {
#pragma unroll
            for (int s = 0; s < 8; s++) rbuf[wv][s * 8 + ch] = acc[s];
        }
        float xh = fmaxf(yc * sgr + shr, 0.f);
        out[(size_t)i * 64 + lane] = xh + rbuf[wv][lane];

        v0c = v0n; v1c = v1n; w0c = w0n; w1c = w1n; yc = yn;
    }
}

// ---------------------------------------------------------------------------
extern "C" void kernel_launch(void* const* d_in, const int* in_sizes, int n_in,
                              void* d_out, int out_size, void* d_ws, size_t ws_size,
                              hipStream_t stream)
{
    const float* p1   = (const float*)d_in[0];
    const float* x1   = (const float*)d_in[1];
    const float* p2   = (const float*)d_in[2];
    const float* x2   = (const float*)d_in[3];
    const int*   knn  = (const int*)d_in[4];
    const int*   iidx = (const int*)d_in[5];
    const float* W1   = (const float*)d_in[6];
    const float* g1   = (const float*)d_in[8];
    const float* be1  = (const float*)d_in[9];
    const float* W2   = (const float*)d_in[10];
    const float* g2   = (const float*)d_in[12];
    const float* be2  = (const float*)d_in[13];
    const float* Wq   = (const float*)d_in[14];
    const float* bq   = (const float*)d_in[15];
    const float* Wk   = (const float*)d_in[16];
    const float* Wv   = (const float*)d_in[18];
    const float* bv   = (const float*)d_in[19];
    const float* gw0  = (const float*)d_in[20];
    const float* bw0  = (const float*)d_in[21];
    const float* Ww1  = (const float*)d_in[22];
    const float* gw1  = (const float*)d_in[24];
    const float* bew1 = (const float*)d_in[25];
    const float* Ww2  = (const float*)d_in[26];
    // b1, b2, bk, bw1, bw2 provably cancel (BN mean-subtraction / softmax shift)

    float* ws   = (float*)d_ws;
    float* y1   = ws + OFF_Y1;
    float* y2   = ws + OFF_Y2;
    __half* xqh  = (__half*)(ws + OFF_XQH);
    __half* xkh  = (__half*)(ws + OFF_XKH);
    __half* xvph = (__half*)(ws + OFF_XVPH);
    __half* w1bh = (__half*)(ws + OFF_W1BH);
    float* st1  = ws + OFF_ST;
    float* st2  = st1 + 128;
    float* st0  = st1 + 256;
    float* stw1 = st1 + 384;
    float* outp = (float*)d_out;

    hipMemsetAsync(st1, 0, 512 * sizeof(float), stream);

    stats12_k<<<197, 256, 0, stream>>>(x1, W1, x2, W2, y1, y2, st1, st2);
    qkv_k<<<782, 256, 0, stream>>>(y1, st1, g1, be1, Wq, bq,
                                   p1, p2, iidx, y2, st2, g2, be2,
                                   Wk, Wv, bv, xqh, xkh, xvph);
    wstats_k<<<1250, 256, 0, stream>>>(xqh, xkh, knn, st0);
    wmlp1_k<<<1250, 256, 0, stream>>>(xqh, xkh, knn, st0, gw0, bw0, Ww1, w1bh);
    w1stats_k<<<512, 256, 0, stream>>>(w1bh, stw1);
    attn_k<<<1250, 256, 0, stream>>>(w1bh, stw1, gw1, bew1, Ww2, knn, xvph,
                                     y1, st1, g1, be1, outp);
}